// Round 1
// baseline (748.088 us; speedup 1.0000x reference)
//
#include <hip/hip_runtime.h>
#include <stdint.h>

#define B_ 8
#define N_ 2048
#define D_ 768

typedef unsigned short u16;
typedef __attribute__((ext_vector_type(8))) short bf16x8;
typedef __attribute__((ext_vector_type(8))) unsigned short u16x8;
typedef __attribute__((ext_vector_type(4))) float f32x4;

static constexpr float INV_SCALE = 0.10825317547305482f; // 3/sqrt(768) = 1/sqrt(768/9)

__device__ __forceinline__ u16 f2bf(float f) {
  union { float f; unsigned u; } v; v.f = f;
  return (u16)((v.u + 0x7FFFu + ((v.u >> 16) & 1u)) >> 16);
}
__device__ __forceinline__ float bf2f(u16 h) {
  union { unsigned u; float f; } v; v.u = ((unsigned)h) << 16;
  return v.f;
}
__device__ __forceinline__ f32x4 mfma16(bf16x8 a, bf16x8 b, f32x4 c) {
  return __builtin_amdgcn_mfma_f32_16x16x32_bf16(a, b, c, 0, 0, 0);
}

// ---------------- K0: cast x, Wq, Wk, Wv to bf16 ----------------
__global__ __launch_bounds__(256) void cast_kernel(
    const float* __restrict__ x, const float* __restrict__ wq,
    const float* __restrict__ wk, const float* __restrict__ wv,
    u16* __restrict__ xb, u16* __restrict__ wqb,
    u16* __restrict__ wkb, u16* __restrict__ wvb) {
  const long NX = (long)B_ * N_ * D_;   // 12582912
  const long NW = (long)D_ * D_;        // 589824
  long i = ((long)blockIdx.x * 256 + threadIdx.x) * 8;
  const float* src; u16* dst; long off;
  if (i < NX) { src = x; dst = xb; off = i; }
  else {
    long j = i - NX;
    int seg = (int)(j / NW);
    off = j - (long)seg * NW;
    src = seg == 0 ? wq : (seg == 1 ? wk : wv);
    dst = seg == 0 ? wqb : (seg == 1 ? wkb : wvb);
  }
  float4 a = *(const float4*)(src + off);
  float4 b = *(const float4*)(src + off + 4);
  u16x8 o;
  o[0]=f2bf(a.x); o[1]=f2bf(a.y); o[2]=f2bf(a.z); o[3]=f2bf(a.w);
  o[4]=f2bf(b.x); o[5]=f2bf(b.y); o[6]=f2bf(b.z); o[7]=f2bf(b.w);
  *(u16x8*)(dst + off) = o;
}

// ---------------- K1: Q/K/V = x @ W^T + b (Q scaled by 1/SCALE) ----------------
// grid (rowtiles=128, coltiles=6, mat=3), block 256 (4 waves, 2x2), wave = 64x64 out
__global__ __launch_bounds__(256) void qkv_gemm(
    const u16* __restrict__ xb,
    const u16* __restrict__ wq, const u16* __restrict__ wk, const u16* __restrict__ wv,
    const float* __restrict__ bq, const float* __restrict__ bk, const float* __restrict__ bv,
    u16* __restrict__ Qs, u16* __restrict__ Kb, u16* __restrict__ Vb) {
  const int mat = blockIdx.z;
  const u16* W = mat == 0 ? wq : (mat == 1 ? wk : wv);
  const float* bias = mat == 0 ? bq : (mat == 1 ? bk : bv);
  u16* out = mat == 0 ? Qs : (mat == 1 ? Kb : Vb);
  const float scl = mat == 0 ? INV_SCALE : 1.0f;

  const int t = threadIdx.x, l = t & 63, w = t >> 6;
  const int rbase = blockIdx.x * 128 + (w >> 1) * 64;
  const int ebase = blockIdx.y * 128 + (w & 1) * 64;
  const int lr = l & 15, lk = (l >> 4) * 8;

  f32x4 acc[4][4] = {};
  for (int d0 = 0; d0 < D_; d0 += 32) {
    bf16x8 a[4], bb[4];
    for (int mf = 0; mf < 4; ++mf)
      a[mf] = *(const bf16x8*)(xb + (long)(rbase + mf * 16 + lr) * D_ + d0 + lk);
    for (int nf = 0; nf < 4; ++nf)
      bb[nf] = *(const bf16x8*)(W + (long)(ebase + nf * 16 + lr) * D_ + d0 + lk);
    for (int mf = 0; mf < 4; ++mf)
      for (int nf = 0; nf < 4; ++nf)
        acc[mf][nf] = mfma16(a[mf], bb[nf], acc[mf][nf]);
  }
  const int orow = (l >> 4) * 4;
  for (int mf = 0; mf < 4; ++mf)
    for (int nf = 0; nf < 4; ++nf) {
      int col = ebase + nf * 16 + lr;
      float bc = bias[col];
      for (int r = 0; r < 4; ++r) {
        int row = rbase + mf * 16 + orow + r;
        out[(long)row * D_ + col] = f2bf((acc[mf][nf][r] + bc) * scl);
      }
    }
}

// ---------------- K2: P = exp(Q.K^T) (scale pre-folded), den partials ----------------
// grid (kblk=16, b=8, qsplit=4), block 256; wave owns 32 k-cols, loops its 512 q rows
__global__ __launch_bounds__(256) void qk_exp(
    const u16* __restrict__ Qs, const u16* __restrict__ Kb,
    u16* __restrict__ P, float* __restrict__ denpart) {
  const int b = blockIdx.y, qs = blockIdx.z;
  const int t = threadIdx.x, l = t & 63, w = t >> 6;
  const int k0 = blockIdx.x * 128 + w * 32;
  const int lr = l & 15, lk = (l >> 4) * 8;
  const long qbB = (long)b * N_;

  float den0 = 0.f, den1 = 0.f;
  for (int it = 0; it < 8; ++it) {
    int q0 = qs * 512 + it * 64;
    f32x4 acc[4][2] = {};
    for (int d0 = 0; d0 < D_; d0 += 32) {
      bf16x8 a[4], bb[2];
      for (int mf = 0; mf < 4; ++mf)
        a[mf] = *(const bf16x8*)(Qs + (qbB + q0 + mf * 16 + lr) * D_ + d0 + lk);
      for (int nf = 0; nf < 2; ++nf)
        bb[nf] = *(const bf16x8*)(Kb + (qbB + k0 + nf * 16 + lr) * D_ + d0 + lk);
      for (int mf = 0; mf < 4; ++mf)
        for (int nf = 0; nf < 2; ++nf)
          acc[mf][nf] = mfma16(a[mf], bb[nf], acc[mf][nf]);
    }
    const int orow = (l >> 4) * 4;
    for (int mf = 0; mf < 4; ++mf)
      for (int nf = 0; nf < 2; ++nf) {
        int kk = k0 + nf * 16 + lr;
        for (int r = 0; r < 4; ++r) {
          int q = q0 + mf * 16 + orow + r;
          float e = __expf(acc[mf][nf][r]);
          u16 pe = f2bf(e);
          P[(qbB + q) * N_ + kk] = pe;
          float ev = bf2f(pe);
          if (nf == 0) den0 += ev; else den1 += ev;
        }
      }
  }
  den0 += __shfl_xor(den0, 16); den0 += __shfl_xor(den0, 32);
  den1 += __shfl_xor(den1, 16); den1 += __shfl_xor(den1, 32);
  if (l < 16) {
    float* dp = denpart + ((long)qs * B_ + b) * N_;
    dp[k0 + l] = den0;
    dp[k0 + 16 + l] = den1;
  }
}

// ---------------- K3: VsT[b][d][k] = V[b][k][d] / den[b][k] ----------------
// grid (dtiles=12, ktiles=32, b=8), block 256, 64x64 tile via LDS
__global__ __launch_bounds__(256) void scale_transpose(
    const u16* __restrict__ Vb, const float* __restrict__ denpart,
    u16* __restrict__ VsT) {
  const int b = blockIdx.z, k0 = blockIdx.y * 64, d0 = blockIdx.x * 64;
  __shared__ float tile[64][65];
  __shared__ float invden[64];
  const int t = threadIdx.x;
  if (t < 64) {
    float s = 0.f;
    for (int qs = 0; qs < 4; ++qs)
      s += denpart[((long)qs * B_ + b) * N_ + k0 + t];
    invden[t] = 1.0f / s;
  }
  __syncthreads();
  for (int idx = t; idx < 4096; idx += 256) {
    int kl = idx >> 6, dl = idx & 63;
    float v = bf2f(Vb[((long)b * N_ + k0 + kl) * D_ + d0 + dl]) * invden[kl];
    tile[dl][kl] = v;
  }
  __syncthreads();
  for (int idx = t; idx < 4096; idx += 256) {
    int dl = idx >> 6, kl = idx & 63;
    VsT[((long)b * D_ + d0 + dl) * N_ + k0 + kl] = f2bf(tile[dl][kl]);
  }
}

// ---------------- K4: out = P @ Vs + x ----------------
// grid (qt=16, dt=6, b=8), block 256 (2x2 waves), wave = 64q x 64d
__global__ __launch_bounds__(256) void pv_gemm(
    const u16* __restrict__ P, const u16* __restrict__ VsT,
    const float* __restrict__ x, float* __restrict__ out) {
  const int b = blockIdx.z;
  const int t = threadIdx.x, l = t & 63, w = t >> 6;
  const int q0 = blockIdx.x * 128 + (w >> 1) * 64;
  const int d0 = blockIdx.y * 128 + (w & 1) * 64;
  const int lr = l & 15, lk = (l >> 4) * 8;
  const u16* Pb = P + (long)b * N_ * N_;
  const u16* Vt = VsT + (long)b * D_ * N_;

  f32x4 acc[4][4] = {};
  for (int kk = 0; kk < N_; kk += 32) {
    bf16x8 a[4], bb[4];
    for (int mf = 0; mf < 4; ++mf)
      a[mf] = *(const bf16x8*)(Pb + (long)(q0 + mf * 16 + lr) * N_ + kk + lk);
    for (int nf = 0; nf < 4; ++nf)
      bb[nf] = *(const bf16x8*)(Vt + (long)(d0 + nf * 16 + lr) * N_ + kk + lk);
    for (int mf = 0; mf < 4; ++mf)
      for (int nf = 0; nf < 4; ++nf)
        acc[mf][nf] = mfma16(a[mf], bb[nf], acc[mf][nf]);
  }
  const int orow = (l >> 4) * 4;
  for (int mf = 0; mf < 4; ++mf)
    for (int nf = 0; nf < 4; ++nf) {
      int dd = d0 + nf * 16 + lr;
      for (int r = 0; r < 4; ++r) {
        int q = q0 + mf * 16 + orow + r;
        long idx = ((long)b * N_ + q) * D_ + dd;
        out[idx] = acc[mf][nf][r] + x[idx];
      }
    }
}

extern "C" void kernel_launch(void* const* d_in, const int* in_sizes, int n_in,
                              void* d_out, int out_size, void* d_ws, size_t ws_size,
                              hipStream_t stream) {
  const float* x  = (const float*)d_in[0];
  const float* Wq = (const float*)d_in[1];
  const float* bq = (const float*)d_in[2];
  const float* Wk = (const float*)d_in[3];
  const float* bk = (const float*)d_in[4];
  const float* Wv = (const float*)d_in[5];
  const float* bv = (const float*)d_in[6];

  char* ws = (char*)d_ws;
  const long NX = (long)B_ * N_ * D_;       // 12582912 elems
  const long NW = (long)D_ * D_;            // 589824 elems
  u16* xb  = (u16*)(ws + 0);                          // 25165824 B
  u16* wqb = (u16*)(ws + 25165824);                   // 1179648 B
  u16* wkb = (u16*)(ws + 26345472);
  u16* wvb = (u16*)(ws + 27525120);
  u16* Qs  = (u16*)(ws + 28704768);                   // 25165824 B
  u16* Kb  = (u16*)(ws + 53870592);
  u16* Vb  = (u16*)(ws + 79036416);
  u16* VsT = (u16*)(ws + 104202240);
  u16* P   = (u16*)(ws + 129368064);                  // 67108864 B
  float* denpart = (float*)(ws + 196476928);          // 262144 B
  (void)NX; (void)NW; (void)in_sizes; (void)n_in; (void)out_size; (void)ws_size;

  cast_kernel<<<7008, 256, 0, stream>>>(x, Wq, Wk, Wv, xb, wqb, wkb, wvb);
  qkv_gemm<<<dim3(128, 6, 3), 256, 0, stream>>>(xb, wqb, wkb, wvb, bq, bk, bv, Qs, Kb, Vb);
  qk_exp<<<dim3(16, 8, 4), 256, 0, stream>>>(Qs, Kb, P, denpart);
  scale_transpose<<<dim3(12, 32, 8), 256, 0, stream>>>(Vb, denpart, VsT);
  pv_gemm<<<dim3(16, 6, 8), 256, 0, stream>>>(P, VsT, x, (float*)d_out);
}

// Round 2
// 276.534 us; speedup vs baseline: 2.7052x; 2.7052x over previous
//
#include <hip/hip_runtime.h>
#include <stdint.h>

#define B_ 8
#define N_ 2048
#define D_ 768

typedef unsigned short u16;
typedef unsigned int u32;
typedef __attribute__((ext_vector_type(8))) short bf16x8;
typedef __attribute__((ext_vector_type(8))) unsigned short u16x8;
typedef __attribute__((ext_vector_type(4))) float f32x4;

static constexpr float INV_SCALE = 0.10825317547305482f; // 3/sqrt(768)

__device__ __forceinline__ u16 f2bf(float f) {
  union { float f; unsigned u; } v; v.f = f;
  return (u16)((v.u + 0x7FFFu + ((v.u >> 16) & 1u)) >> 16);
}
__device__ __forceinline__ float bf2f(u16 h) {
  union { unsigned u; float f; } v; v.u = ((unsigned)h) << 16;
  return v.f;
}
__device__ __forceinline__ f32x4 mfma16(bf16x8 a, bf16x8 b, f32x4 c) {
  return __builtin_amdgcn_mfma_f32_16x16x32_bf16(a, b, c, 0, 0, 0);
}
// async global->LDS, 16B per lane. LDS dest must be wave-uniform base;
// lane i lands at base + i*16 bytes.
__device__ __forceinline__ void gl_lds16(const u16* g, u16* l) {
  __builtin_amdgcn_global_load_lds(
      (const __attribute__((address_space(1))) u32*)g,
      (__attribute__((address_space(3))) u32*)l, 16, 0, 0);
}

// ---------------- K0: cast x, Wq, Wk, Wv to bf16 ----------------
__global__ __launch_bounds__(256) void cast_kernel(
    const float* __restrict__ x, const float* __restrict__ wq,
    const float* __restrict__ wk, const float* __restrict__ wv,
    u16* __restrict__ xb, u16* __restrict__ wqb,
    u16* __restrict__ wkb, u16* __restrict__ wvb) {
  const long NX = (long)B_ * N_ * D_;
  const long NW = (long)D_ * D_;
  long i = ((long)blockIdx.x * 256 + threadIdx.x) * 8;
  const float* src; u16* dst; long off;
  if (i < NX) { src = x; dst = xb; off = i; }
  else {
    long j = i - NX;
    int seg = (int)(j / NW);
    off = j - (long)seg * NW;
    src = seg == 0 ? wq : (seg == 1 ? wk : wv);
    dst = seg == 0 ? wqb : (seg == 1 ? wkb : wvb);
  }
  float4 a = *(const float4*)(src + off);
  float4 b = *(const float4*)(src + off + 4);
  u16x8 o;
  o[0]=f2bf(a.x); o[1]=f2bf(a.y); o[2]=f2bf(a.z); o[3]=f2bf(a.w);
  o[4]=f2bf(b.x); o[5]=f2bf(b.y); o[6]=f2bf(b.z); o[7]=f2bf(b.w);
  *(u16x8*)(dst + off) = o;
}

// ---------------- K1: Q/K/V = x @ W^T + b (Q scaled) — m97 structure ----------------
// grid (128, 6, 3), block 256 (2x2 waves of 64x64), BK=32, LDS-staged
__global__ __launch_bounds__(256) void qkv_gemm(
    const u16* __restrict__ xb,
    const u16* __restrict__ wq, const u16* __restrict__ wk, const u16* __restrict__ wv,
    const float* __restrict__ bq, const float* __restrict__ bk, const float* __restrict__ bv,
    u16* __restrict__ Qs, u16* __restrict__ Kb, u16* __restrict__ Vb) {
  __shared__ u16 As[128 * 32];
  __shared__ u16 Bs[128 * 32];
  const int mat = blockIdx.z;
  const u16* W = mat == 0 ? wq : (mat == 1 ? wk : wv);
  const float* bias = mat == 0 ? bq : (mat == 1 ? bk : bv);
  u16* out = mat == 0 ? Qs : (mat == 1 ? Kb : Vb);
  const float scl = mat == 0 ? INV_SCALE : 1.0f;

  const int t = threadIdx.x, l = t & 63, w = t >> 6;
  const int rbase = blockIdx.x * 128, cbase = blockIdx.y * 128;
  const int lr = l & 15, lk = (l >> 4) * 8;
  const int ldrow = l >> 2, ldcol = (l & 3) * 8;   // staging: 16 rows x 64B per wave-call
  const int ar = (w >> 1) * 64, br = (w & 1) * 64;

  f32x4 acc[4][4] = {};
  for (int d0 = 0; d0 < D_; d0 += 32) {
    #pragma unroll
    for (int c = 0; c < 2; ++c) {
      const int chunk = w * 2 + c;
      gl_lds16(xb + (long)(rbase + chunk * 16 + ldrow) * D_ + d0 + ldcol, As + chunk * 512);
      gl_lds16(W  + (long)(cbase + chunk * 16 + ldrow) * D_ + d0 + ldcol, Bs + chunk * 512);
    }
    __syncthreads();
    bf16x8 a[4], bb[4];
    #pragma unroll
    for (int mf = 0; mf < 4; ++mf) a[mf]  = *(const bf16x8*)(As + (ar + mf * 16 + lr) * 32 + lk);
    #pragma unroll
    for (int nf = 0; nf < 4; ++nf) bb[nf] = *(const bf16x8*)(Bs + (br + nf * 16 + lr) * 32 + lk);
    #pragma unroll
    for (int mf = 0; mf < 4; ++mf)
      #pragma unroll
      for (int nf = 0; nf < 4; ++nf)
        acc[mf][nf] = mfma16(a[mf], bb[nf], acc[mf][nf]);
    __syncthreads();
  }
  const int orow = (l >> 4) * 4;
  #pragma unroll
  for (int mf = 0; mf < 4; ++mf)
    #pragma unroll
    for (int nf = 0; nf < 4; ++nf) {
      int col = cbase + br + nf * 16 + lr;
      float bc = bias[col];
      #pragma unroll
      for (int r = 0; r < 4; ++r) {
        int row = rbase + ar + mf * 16 + orow + r;
        out[(long)row * D_ + col] = f2bf((acc[mf][nf][r] + bc) * scl);
      }
    }
}

// ---------------- K2: P = exp(Q.K^T), den partials — m97 structure ----------------
// grid (16 kblk, 16 qblk, 8 b), block 256; block computes 128q x 128k
__global__ __launch_bounds__(256) void qk_exp(
    const u16* __restrict__ Qs, const u16* __restrict__ Kb,
    u16* __restrict__ P, float* __restrict__ denpart) {
  __shared__ u16 As[128 * 32];
  __shared__ u16 Bs[128 * 32];
  __shared__ float dl[2][128];
  const int kblk = blockIdx.x, qblk = blockIdx.y, b = blockIdx.z;
  const int t = threadIdx.x, l = t & 63, w = t >> 6;
  const int lr = l & 15, lk = (l >> 4) * 8;
  const int ldrow = l >> 2, ldcol = (l & 3) * 8;
  const int ar = (w >> 1) * 64, br = (w & 1) * 64;
  const long qg = (long)b * N_ + qblk * 128;  // global Q row base
  const long kg = (long)b * N_ + kblk * 128;  // global K row base

  f32x4 acc[4][4] = {};
  for (int d0 = 0; d0 < D_; d0 += 32) {
    #pragma unroll
    for (int c = 0; c < 2; ++c) {
      const int chunk = w * 2 + c;
      gl_lds16(Qs + (qg + chunk * 16 + ldrow) * D_ + d0 + ldcol, As + chunk * 512);
      gl_lds16(Kb + (kg + chunk * 16 + ldrow) * D_ + d0 + ldcol, Bs + chunk * 512);
    }
    __syncthreads();
    bf16x8 a[4], bb[4];
    #pragma unroll
    for (int mf = 0; mf < 4; ++mf) a[mf]  = *(const bf16x8*)(As + (ar + mf * 16 + lr) * 32 + lk);
    #pragma unroll
    for (int nf = 0; nf < 4; ++nf) bb[nf] = *(const bf16x8*)(Bs + (br + nf * 16 + lr) * 32 + lk);
    #pragma unroll
    for (int mf = 0; mf < 4; ++mf)
      #pragma unroll
      for (int nf = 0; nf < 4; ++nf)
        acc[mf][nf] = mfma16(a[mf], bb[nf], acc[mf][nf]);
    __syncthreads();
  }
  // epilogue: exp, store P (bf16), per-column sums
  const int orow = (l >> 4) * 4;
  float csum[4] = {0.f, 0.f, 0.f, 0.f};
  #pragma unroll
  for (int mf = 0; mf < 4; ++mf)
    #pragma unroll
    for (int nf = 0; nf < 4; ++nf) {
      long kk = kblk * 128 + br + nf * 16 + lr;
      #pragma unroll
      for (int r = 0; r < 4; ++r) {
        long q = qblk * 128 + ar + mf * 16 + orow + r;
        float e = __expf(acc[mf][nf][r]);
        u16 pe = f2bf(e);
        P[((long)b * N_ + q) * N_ + kk] = pe;
        csum[nf] += bf2f(pe);
      }
    }
  #pragma unroll
  for (int nf = 0; nf < 4; ++nf) {
    csum[nf] += __shfl_xor(csum[nf], 16);
    csum[nf] += __shfl_xor(csum[nf], 32);
  }
  if (l < 16) {
    #pragma unroll
    for (int nf = 0; nf < 4; ++nf)
      dl[w >> 1][br + nf * 16 + l] = csum[nf];
  }
  __syncthreads();
  if (t < 128)
    denpart[((long)qblk * B_ + b) * N_ + kblk * 128 + t] = dl[0][t] + dl[1][t];
}

// ---------------- K3: VsT[b][d][k] = V[b][k][d] / den[b][k] ----------------
__global__ __launch_bounds__(256) void scale_transpose(
    const u16* __restrict__ Vb, const float* __restrict__ denpart,
    u16* __restrict__ VsT) {
  const int b = blockIdx.z, k0 = blockIdx.y * 64, d0 = blockIdx.x * 64;
  __shared__ float tile[64][65];
  __shared__ float invden[64];
  const int t = threadIdx.x;
  if (t < 64) {
    float s = 0.f;
    for (int qs = 0; qs < 16; ++qs)
      s += denpart[((long)qs * B_ + b) * N_ + k0 + t];
    invden[t] = 1.0f / s;
  }
  __syncthreads();
  for (int idx = t; idx < 4096; idx += 256) {
    int kl = idx >> 6, dl = idx & 63;
    float v = bf2f(Vb[((long)b * N_ + k0 + kl) * D_ + d0 + dl]) * invden[kl];
    tile[dl][kl] = v;
  }
  __syncthreads();
  for (int idx = t; idx < 4096; idx += 256) {
    int dl = idx >> 6, kl = idx & 63;
    VsT[((long)b * D_ + d0 + dl) * N_ + k0 + kl] = f2bf(tile[dl][kl]);
  }
}

// ---------------- K4: out = P @ Vs + x — m97 structure ----------------
// grid (16 qt, 6 dt, 8 b), block 256; block computes 128q x 128d, K=2048
__global__ __launch_bounds__(256) void pv_gemm(
    const u16* __restrict__ P, const u16* __restrict__ VsT,
    const float* __restrict__ x, float* __restrict__ out) {
  __shared__ u16 As[128 * 32];
  __shared__ u16 Bs[128 * 32];
  const int b = blockIdx.z;
  const int t = threadIdx.x, l = t & 63, w = t >> 6;
  const int lr = l & 15, lk = (l >> 4) * 8;
  const int ldrow = l >> 2, ldcol = (l & 3) * 8;
  const int ar = (w >> 1) * 64, br = (w & 1) * 64;
  const int q0 = blockIdx.x * 128, d0 = blockIdx.y * 128;
  const u16* Pb = P + (long)b * N_ * N_;
  const u16* Vt = VsT + (long)b * D_ * N_;

  f32x4 acc[4][4] = {};
  for (int kk = 0; kk < N_; kk += 32) {
    #pragma unroll
    for (int c = 0; c < 2; ++c) {
      const int chunk = w * 2 + c;
      gl_lds16(Pb + (long)(q0 + chunk * 16 + ldrow) * N_ + kk + ldcol, As + chunk * 512);
      gl_lds16(Vt + (long)(d0 + chunk * 16 + ldrow) * N_ + kk + ldcol, Bs + chunk * 512);
    }
    __syncthreads();
    bf16x8 a[4], bb[4];
    #pragma unroll
    for (int mf = 0; mf < 4; ++mf) a[mf]  = *(const bf16x8*)(As + (ar + mf * 16 + lr) * 32 + lk);
    #pragma unroll
    for (int nf = 0; nf < 4; ++nf) bb[nf] = *(const bf16x8*)(Bs + (br + nf * 16 + lr) * 32 + lk);
    #pragma unroll
    for (int mf = 0; mf < 4; ++mf)
      #pragma unroll
      for (int nf = 0; nf < 4; ++nf)
        acc[mf][nf] = mfma16(a[mf], bb[nf], acc[mf][nf]);
    __syncthreads();
  }
  const int orow = (l >> 4) * 4;
  #pragma unroll
  for (int mf = 0; mf < 4; ++mf)
    #pragma unroll
    for (int nf = 0; nf < 4; ++nf) {
      int dd = d0 + br + nf * 16 + lr;
      #pragma unroll
      for (int r = 0; r < 4; ++r) {
        int q = q0 + ar + mf * 16 + orow + r;
        long idx = ((long)b * N_ + q) * D_ + dd;
        out[idx] = acc[mf][nf][r] + x[idx];
      }
    }
}

extern "C" void kernel_launch(void* const* d_in, const int* in_sizes, int n_in,
                              void* d_out, int out_size, void* d_ws, size_t ws_size,
                              hipStream_t stream) {
  const float* x  = (const float*)d_in[0];
  const float* Wq = (const float*)d_in[1];
  const float* bq = (const float*)d_in[2];
  const float* Wk = (const float*)d_in[3];
  const float* bk = (const float*)d_in[4];
  const float* Wv = (const float*)d_in[5];
  const float* bv = (const float*)d_in[6];

  char* ws = (char*)d_ws;
  // denpart (2 MB, 16 q-splits) overlaps xb's region: xb is only live
  // cast->qkv_gemm; denpart is written by qk_exp (after) and read by
  // scale_transpose. Each call rewrites xb first -> deterministic.
  float* denpart = (float*)(ws + 0);
  u16* xb  = (u16*)(ws + 0);                          // 25165824 B
  u16* wqb = (u16*)(ws + 25165824);                   // 1179648 B
  u16* wkb = (u16*)(ws + 26345472);
  u16* wvb = (u16*)(ws + 27525120);
  u16* Qs  = (u16*)(ws + 28704768);                   // 25165824 B
  u16* Kb  = (u16*)(ws + 53870592);
  u16* Vb  = (u16*)(ws + 79036416);
  u16* VsT = (u16*)(ws + 104202240);
  u16* P   = (u16*)(ws + 129368064);                  // 67108864 B
  (void)in_sizes; (void)n_in; (void)out_size; (void)ws_size;

  cast_kernel<<<7008, 256, 0, stream>>>(x, Wq, Wk, Wv, xb, wqb, wkb, wvb);
  qkv_gemm<<<dim3(128, 6, 3), 256, 0, stream>>>(xb, wqb, wkb, wvb, bq, bk, bv, Qs, Kb, Vb);
  qk_exp<<<dim3(16, 16, 8), 256, 0, stream>>>(Qs, Kb, P, denpart);
  scale_transpose<<<dim3(12, 32, 8), 256, 0, stream>>>(Vb, denpart, VsT);
  pv_gemm<<<dim3(16, 6, 8), 256, 0, stream>>>(P, VsT, x, (float*)d_out);
}

// Round 3
// 270.098 us; speedup vs baseline: 2.7697x; 1.0238x over previous
//
#include <hip/hip_runtime.h>
#include <stdint.h>

#define B_ 8
#define N_ 2048
#define D_ 768

typedef unsigned short u16;
typedef unsigned int u32;
typedef __attribute__((ext_vector_type(8))) short bf16x8;
typedef __attribute__((ext_vector_type(8))) unsigned short u16x8;
typedef __attribute__((ext_vector_type(4))) float f32x4;

static constexpr float INV_SCALE = 0.10825317547305482f; // 3/sqrt(768)

__device__ __forceinline__ u16 f2bf(float f) {
  union { float f; unsigned u; } v; v.f = f;
  return (u16)((v.u + 0x7FFFu + ((v.u >> 16) & 1u)) >> 16);
}
__device__ __forceinline__ float bf2f(u16 h) {
  union { unsigned u; float f; } v; v.u = ((unsigned)h) << 16;
  return v.f;
}
__device__ __forceinline__ f32x4 mfma16(bf16x8 a, bf16x8 b, f32x4 c) {
  return __builtin_amdgcn_mfma_f32_16x16x32_bf16(a, b, c, 0, 0, 0);
}
__device__ __forceinline__ void gl_lds16(const u16* g, u16* l) {
  __builtin_amdgcn_global_load_lds(
      (const __attribute__((address_space(1))) u32*)g,
      (__attribute__((address_space(3))) u32*)l, 16, 0, 0);
}

// ---------------- K0: cast x, Wq, Wk, Wv to bf16 ----------------
__global__ __launch_bounds__(256) void cast_kernel(
    const float* __restrict__ x, const float* __restrict__ wq,
    const float* __restrict__ wk, const float* __restrict__ wv,
    u16* __restrict__ xb, u16* __restrict__ wqb,
    u16* __restrict__ wkb, u16* __restrict__ wvb) {
  const long NX = (long)B_ * N_ * D_;
  const long NW = (long)D_ * D_;
  long i = ((long)blockIdx.x * 256 + threadIdx.x) * 8;
  const float* src; u16* dst; long off;
  if (i < NX) { src = x; dst = xb; off = i; }
  else {
    long j = i - NX;
    int seg = (int)(j / NW);
    off = j - (long)seg * NW;
    src = seg == 0 ? wq : (seg == 1 ? wk : wv);
    dst = seg == 0 ? wqb : (seg == 1 ? wkb : wvb);
  }
  float4 a = *(const float4*)(src + off);
  float4 b = *(const float4*)(src + off + 4);
  u16x8 o;
  o[0]=f2bf(a.x); o[1]=f2bf(a.y); o[2]=f2bf(a.z); o[3]=f2bf(a.w);
  o[4]=f2bf(b.x); o[5]=f2bf(b.y); o[6]=f2bf(b.z); o[7]=f2bf(b.w);
  *(u16x8*)(dst + off) = o;
}

// ---------------- shared 128x128 BK=32 double-buffered pipelined GEMM core ----
// Ag/Bg: pre-offset to block's 128-row panels, contraction contiguous.
// Swizzle: physical slot = logical slot ^ ((row>>1)&3)  (slots = 16B units in a
// 64B row). Writer pre-swizzles the GLOBAL source column; reader swizzles the
// ds_read address. Both sides, same involution (rule 21).
__device__ __forceinline__ void gemm_main(
    const u16* __restrict__ Ag, long lda,
    const u16* __restrict__ Bg, long ldb,
    int ksteps, f32x4 (&acc)[4][4]) {
  __shared__ u16 As0[128 * 32];
  __shared__ u16 As1[128 * 32];
  __shared__ u16 Bs0[128 * 32];
  __shared__ u16 Bs1[128 * 32];
  const int t = threadIdx.x, l = t & 63, w = t >> 6;
  const int lr = l & 15;
  const int srow = l >> 2;                            // staging row within 16-row chunk
  const int scol = (((l & 3) ^ ((l >> 3) & 3)) * 8);  // pre-swizzled source col (elems)
  const int ar = (w >> 1) * 64, br = (w & 1) * 64;
  const int rslot = (((l >> 4) ^ ((lr >> 1) & 3)) * 8); // swizzled read slot (elems)

  auto STAGE = [&](u16* As, u16* Bs, int kofs) {
    #pragma unroll
    for (int c = 0; c < 2; ++c) {
      int ch = w * 2 + c;
      gl_lds16(Ag + (long)(ch * 16 + srow) * lda + kofs + scol, As + ch * 512);
      gl_lds16(Bg + (long)(ch * 16 + srow) * ldb + kofs + scol, Bs + ch * 512);
    }
    asm volatile("" ::: "memory");
  };
  auto COMPUTE = [&](const u16* As, const u16* Bs) {
    bf16x8 a[4], bb[4];
    #pragma unroll
    for (int mf = 0; mf < 4; ++mf)
      a[mf] = *(const bf16x8*)(As + (ar + mf * 16 + lr) * 32 + rslot);
    #pragma unroll
    for (int nf = 0; nf < 4; ++nf)
      bb[nf] = *(const bf16x8*)(Bs + (br + nf * 16 + lr) * 32 + rslot);
    __builtin_amdgcn_s_setprio(1);
    #pragma unroll
    for (int mf = 0; mf < 4; ++mf)
      #pragma unroll
      for (int nf = 0; nf < 4; ++nf)
        acc[mf][nf] = mfma16(a[mf], bb[nf], acc[mf][nf]);
    __builtin_amdgcn_s_setprio(0);
    asm volatile("" ::: "memory");
  };

  STAGE(As0, Bs0, 0);
  for (int ks = 0; ks < ksteps; ks += 2) {
    STAGE(As1, Bs1, (ks + 1) * 32);               // prefetch tile ks+1
    asm volatile("s_waitcnt vmcnt(4)" ::: "memory"); // tile ks landed; ks+1 in flight
    __builtin_amdgcn_s_barrier();
    COMPUTE(As0, Bs0);
    __builtin_amdgcn_s_barrier();
    if (ks + 2 < ksteps) {
      STAGE(As0, Bs0, (ks + 2) * 32);             // prefetch tile ks+2
      asm volatile("s_waitcnt vmcnt(4)" ::: "memory");
    } else {
      asm volatile("s_waitcnt vmcnt(0)" ::: "memory");
    }
    __builtin_amdgcn_s_barrier();
    COMPUTE(As1, Bs1);
    __builtin_amdgcn_s_barrier();
  }
}

// ---------------- K1: Q/K/V = x @ W^T + b (Q scaled) ----------------
// 1-D grid 2304 (= 128 rt x 6 ct x 3 mat), XCD-swizzled
__global__ __launch_bounds__(256) void qkv_gemm(
    const u16* __restrict__ xb,
    const u16* __restrict__ wq, const u16* __restrict__ wk, const u16* __restrict__ wv,
    const float* __restrict__ bq, const float* __restrict__ bk, const float* __restrict__ bv,
    u16* __restrict__ Qs, u16* __restrict__ Kb, u16* __restrict__ Vb) {
  const int lin = blockIdx.x;
  const int L = (lin & 7) * 288 + (lin >> 3);
  const int rt = L % 128, ct = (L / 128) % 6, mat = L / 768;
  const u16* W = mat == 0 ? wq : (mat == 1 ? wk : wv);
  const float* bias = mat == 0 ? bq : (mat == 1 ? bk : bv);
  u16* out = mat == 0 ? Qs : (mat == 1 ? Kb : Vb);
  const float scl = mat == 0 ? INV_SCALE : 1.0f;
  const int rbase = rt * 128, cbase = ct * 128;

  f32x4 acc[4][4] = {};
  gemm_main(xb + (long)rbase * D_, D_, W + (long)cbase * D_, D_, D_ / 32, acc);

  const int l = threadIdx.x & 63, w = threadIdx.x >> 6;
  const int lr = l & 15, orow = (l >> 4) * 4;
  const int ar = (w >> 1) * 64, br = (w & 1) * 64;
  #pragma unroll
  for (int mf = 0; mf < 4; ++mf)
    #pragma unroll
    for (int nf = 0; nf < 4; ++nf) {
      int col = cbase + br + nf * 16 + lr;
      float bc = bias[col];
      #pragma unroll
      for (int r = 0; r < 4; ++r) {
        int row = rbase + ar + mf * 16 + orow + r;
        out[(long)row * D_ + col] = f2bf((acc[mf][nf][r] + bc) * scl);
      }
    }
}

// ---------------- K2: P = exp(Q.K^T), den partials ----------------
// 1-D grid 2048 (= 16 kb x 16 qb x 8 b), XCD-swizzled
__global__ __launch_bounds__(256) void qk_exp(
    const u16* __restrict__ Qs, const u16* __restrict__ Kb,
    u16* __restrict__ P, float* __restrict__ denpart) {
  __shared__ float dl[2][128];
  const int lin = blockIdx.x;
  const int L = (lin & 7) * 256 + (lin >> 3);
  const int kblk = L % 16, qblk = (L / 16) % 16, b = L / 256;

  f32x4 acc[4][4] = {};
  gemm_main(Qs + ((long)b * N_ + qblk * 128) * D_, D_,
            Kb + ((long)b * N_ + kblk * 128) * D_, D_, D_ / 32, acc);

  const int tt = threadIdx.x, l = tt & 63, w = tt >> 6;
  const int lr = l & 15, orow = (l >> 4) * 4;
  const int ar = (w >> 1) * 64, br = (w & 1) * 64;
  float csum[4] = {0.f, 0.f, 0.f, 0.f};
  #pragma unroll
  for (int mf = 0; mf < 4; ++mf)
    #pragma unroll
    for (int nf = 0; nf < 4; ++nf) {
      long kk = kblk * 128 + br + nf * 16 + lr;
      #pragma unroll
      for (int r = 0; r < 4; ++r) {
        long q = qblk * 128 + ar + mf * 16 + orow + r;
        float e = __expf(acc[mf][nf][r]);
        u16 pe = f2bf(e);
        P[((long)b * N_ + q) * N_ + kk] = pe;
        csum[nf] += bf2f(pe);
      }
    }
  #pragma unroll
  for (int nf = 0; nf < 4; ++nf) {
    csum[nf] += __shfl_xor(csum[nf], 16);
    csum[nf] += __shfl_xor(csum[nf], 32);
  }
  __syncthreads();
  if (l < 16) {
    #pragma unroll
    for (int nf = 0; nf < 4; ++nf)
      dl[w >> 1][br + nf * 16 + l] = csum[nf];
  }
  __syncthreads();
  if (tt < 128)
    denpart[((long)qblk * B_ + b) * N_ + kblk * 128 + tt] = dl[0][tt] + dl[1][tt];
}

// ---------------- K3: VsT[b][d][k] = V[b][k][d] / den[b][k] ----------------
__global__ __launch_bounds__(256) void scale_transpose(
    const u16* __restrict__ Vb, const float* __restrict__ denpart,
    u16* __restrict__ VsT) {
  const int b = blockIdx.z, k0 = blockIdx.y * 64, d0 = blockIdx.x * 64;
  __shared__ float tile[64][65];
  __shared__ float invden[64];
  const int t = threadIdx.x;
  if (t < 64) {
    float s = 0.f;
    for (int qs = 0; qs < 16; ++qs)
      s += denpart[((long)qs * B_ + b) * N_ + k0 + t];
    invden[t] = 1.0f / s;
  }
  __syncthreads();
  for (int idx = t; idx < 4096; idx += 256) {
    int kl = idx >> 6, dl = idx & 63;
    float v = bf2f(Vb[((long)b * N_ + k0 + kl) * D_ + d0 + dl]) * invden[kl];
    tile[dl][kl] = v;
  }
  __syncthreads();
  for (int idx = t; idx < 4096; idx += 256) {
    int dl = idx >> 6, kl = idx & 63;
    VsT[((long)b * D_ + d0 + dl) * N_ + k0 + kl] = f2bf(tile[dl][kl]);
  }
}

// ---------------- K4: out = P @ Vs + x ----------------
// 1-D grid 768 (= 16 qt x 6 dt x 8 b), XCD-swizzled (96 blocks/XCD = one b)
__global__ __launch_bounds__(256) void pv_gemm(
    const u16* __restrict__ P, const u16* __restrict__ VsT,
    const float* __restrict__ x, float* __restrict__ out) {
  const int lin = blockIdx.x;
  const int L = (lin & 7) * 96 + (lin >> 3);
  const int qt = L % 16, dt = (L / 16) % 6, b = L / 96;
  const int q0 = qt * 128, d0 = dt * 128;

  f32x4 acc[4][4] = {};
  gemm_main(P + ((long)b * N_ + q0) * N_, N_,
            VsT + ((long)b * D_ + d0) * N_, N_, N_ / 32, acc);

  const int l = threadIdx.x & 63, w = threadIdx.x >> 6;
  const int lr = l & 15, orow = (l >> 4) * 4;
  const int ar = (w >> 1) * 64, br = (w & 1) * 64;
  #pragma unroll
  for (int mf = 0; mf < 4; ++mf)
    #pragma unroll
    for (int nf = 0; nf < 4; ++nf) {
      int dd = d0 + br + nf * 16 + lr;
      #pragma unroll
      for (int r = 0; r < 4; ++r) {
        int q = q0 + ar + mf * 16 + orow + r;
        long idx = ((long)b * N_ + q) * D_ + dd;
        out[idx] = acc[mf][nf][r] + x[idx];
      }
    }
}

extern "C" void kernel_launch(void* const* d_in, const int* in_sizes, int n_in,
                              void* d_out, int out_size, void* d_ws, size_t ws_size,
                              hipStream_t stream) {
  const float* x  = (const float*)d_in[0];
  const float* Wq = (const float*)d_in[1];
  const float* bq = (const float*)d_in[2];
  const float* Wk = (const float*)d_in[3];
  const float* bk = (const float*)d_in[4];
  const float* Wv = (const float*)d_in[5];
  const float* bv = (const float*)d_in[6];

  char* ws = (char*)d_ws;
  // denpart overlaps xb (xb live only cast->qkv_gemm; denpart written after).
  float* denpart = (float*)(ws + 0);
  u16* xb  = (u16*)(ws + 0);                          // 25165824 B
  u16* wqb = (u16*)(ws + 25165824);
  u16* wkb = (u16*)(ws + 26345472);
  u16* wvb = (u16*)(ws + 27525120);
  u16* Qs  = (u16*)(ws + 28704768);
  u16* Kb  = (u16*)(ws + 53870592);
  u16* Vb  = (u16*)(ws + 79036416);
  u16* VsT = (u16*)(ws + 104202240);
  u16* P   = (u16*)(ws + 129368064);                  // 67108864 B
  (void)in_sizes; (void)n_in; (void)out_size; (void)ws_size;

  cast_kernel<<<7008, 256, 0, stream>>>(x, Wq, Wk, Wv, xb, wqb, wkb, wvb);
  qkv_gemm<<<2304, 256, 0, stream>>>(xb, wqb, wkb, wvb, bq, bk, bv, Qs, Kb, Vb);
  qk_exp<<<2048, 256, 0, stream>>>(Qs, Kb, P, denpart);
  scale_transpose<<<dim3(12, 32, 8), 256, 0, stream>>>(Vb, denpart, VsT);
  pv_gemm<<<768, 256, 0, stream>>>(P, VsT, x, (float*)d_out);
}